// Round 1
// baseline (28558.612 us; speedup 1.0000x reference)
//
#include <hip/hip_runtime.h>
#include <cstddef>

__device__ __forceinline__ float sigm(float x) { return 1.f / (1.f + __expf(-x)); }
__device__ __forceinline__ float tanh_(float x) { return 1.f - 2.f / (__expf(2.f * x) + 1.f); }

#define AGLD(p)    __hip_atomic_load((p),  __ATOMIC_RELAXED, __HIP_MEMORY_SCOPE_AGENT)
#define AGST(p, v) __hip_atomic_store((p), (v), __ATOMIC_RELAXED, __HIP_MEMORY_SCOPE_AGENT)
#define AGADD(p,v) __hip_atomic_fetch_add((p), (v), __ATOMIC_RELAXED, __HIP_MEMORY_SCOPE_AGENT)

// 16-wide fp32 dot block: accumulates into a0..a3 (declared by caller)
#define DOT16(wp, hp, kk) do { \
    float4 w0_ = *(const float4*)((wp) + (kk));      float4 x0_ = *(const float4*)((hp) + (kk)); \
    float4 w1_ = *(const float4*)((wp) + (kk) + 4);  float4 x1_ = *(const float4*)((hp) + (kk) + 4); \
    float4 w2_ = *(const float4*)((wp) + (kk) + 8);  float4 x2_ = *(const float4*)((hp) + (kk) + 8); \
    float4 w3_ = *(const float4*)((wp) + (kk) + 12); float4 x3_ = *(const float4*)((hp) + (kk) + 12); \
    a0 = fmaf(w0_.x, x0_.x, a0); a0 = fmaf(w0_.y, x0_.y, a0); a0 = fmaf(w0_.z, x0_.z, a0); a0 = fmaf(w0_.w, x0_.w, a0); \
    a1 = fmaf(w1_.x, x1_.x, a1); a1 = fmaf(w1_.y, x1_.y, a1); a1 = fmaf(w1_.z, x1_.z, a1); a1 = fmaf(w1_.w, x1_.w, a1); \
    a2 = fmaf(w2_.x, x2_.x, a2); a2 = fmaf(w2_.y, x2_.y, a2); a2 = fmaf(w2_.z, x2_.z, a2); a2 = fmaf(w2_.w, x2_.w, a2); \
    a3 = fmaf(w3_.x, x3_.x, a3); a3 = fmaf(w3_.y, x3_.y, a3); a3 = fmaf(w3_.z, x3_.z, a3); a3 = fmaf(w3_.w, x3_.w, a3); \
  } while (0)

// ---------------- K1: embed = relu(inputs @ W_e^T + b_e), layout [s][b][e] ----------------
__global__ __launch_bounds__(256) void k_embed(
    const float* __restrict__ inp, const float* __restrict__ We,
    const float* __restrict__ be, float* __restrict__ emb)
{
  __shared__ float sA[32 * 68];
  __shared__ float sW[32 * 132];
  const int tid = threadIdx.x;
  const int b  = blockIdx.x >> 4;
  const int s0 = (blockIdx.x & 15) << 6;
  float acc[4][8];
#pragma unroll
  for (int i = 0; i < 4; ++i)
#pragma unroll
    for (int j = 0; j < 8; ++j) acc[i][j] = 0.f;
  const int m4 = (tid & 15) << 2;
  const int e8 = (tid >> 4) << 3;
  const float* Ab = inp + ((size_t)(b << 10) + s0) * 1024;
  const int ms = tid >> 2, kq = tid & 3;
  const int es = tid >> 1, kq2 = tid & 1;
  for (int k0 = 0; k0 < 1024; k0 += 32) {
    __syncthreads();
    {
      const float* src = Ab + (size_t)ms * 1024 + k0 + (kq << 3);
      float4 v0 = *(const float4*)(src);
      float4 v1 = *(const float4*)(src + 4);
      int kb = kq << 3;
      sA[(kb+0)*68+ms] = v0.x; sA[(kb+1)*68+ms] = v0.y;
      sA[(kb+2)*68+ms] = v0.z; sA[(kb+3)*68+ms] = v0.w;
      sA[(kb+4)*68+ms] = v1.x; sA[(kb+5)*68+ms] = v1.y;
      sA[(kb+6)*68+ms] = v1.z; sA[(kb+7)*68+ms] = v1.w;
    }
    {
      const float* src = We + (size_t)es * 1024 + k0 + (kq2 << 4);
#pragma unroll
      for (int q = 0; q < 4; ++q) {
        float4 v = *(const float4*)(src + (q << 2));
        int kb = (kq2 << 4) + (q << 2);
        sW[(kb+0)*132+es] = v.x; sW[(kb+1)*132+es] = v.y;
        sW[(kb+2)*132+es] = v.z; sW[(kb+3)*132+es] = v.w;
      }
    }
    __syncthreads();
#pragma unroll 4
    for (int kk = 0; kk < 32; ++kk) {
      float4 a4 = *(const float4*)&sA[kk*68 + m4];
      float4 b0 = *(const float4*)&sW[kk*132 + e8];
      float4 b1 = *(const float4*)&sW[kk*132 + e8 + 4];
      float av[4] = {a4.x, a4.y, a4.z, a4.w};
      float bv[8] = {b0.x, b0.y, b0.z, b0.w, b1.x, b1.y, b1.z, b1.w};
#pragma unroll
      for (int i = 0; i < 4; ++i)
#pragma unroll
        for (int j = 0; j < 8; ++j) acc[i][j] = fmaf(av[i], bv[j], acc[i][j]);
    }
  }
#pragma unroll
  for (int i = 0; i < 4; ++i) {
    int s = s0 + m4 + i;
#pragma unroll
    for (int j = 0; j < 8; ++j) {
      float v = acc[i][j] + be[e8 + j];
      emb[((size_t)(s << 5) + b) * 128 + e8 + j] = v > 0.f ? v : 0.f;
    }
  }
}

// ---------------- K2: a = relu(embed @ Wa1^T + ba1) @ Wa2^T + ba2, layout [s*32+b][3] ----------------
__global__ __launch_bounds__(256) void k_attn(
    const float* __restrict__ emb, const float* __restrict__ Wa1,
    const float* __restrict__ ba1, const float* __restrict__ Wa2,
    const float* __restrict__ ba2, float* __restrict__ aw)
{
  __shared__ float sE[2 * 128];
  __shared__ float sH[2 * 128];
  const int tid = threadIdx.x;
  const int rs0 = blockIdx.x * 2;
  sE[tid] = emb[(size_t)rs0 * 128 + tid];
  __syncthreads();
  const int half = tid >> 7, j = tid & 127;
  const float* w = Wa1 + j * 128;
  const float* e = sE + half * 128;
  float a0 = 0.f, a1 = 0.f, a2 = 0.f, a3 = 0.f;
  for (int k = 0; k < 128; k += 16) DOT16(w, e, k);
  float h = (a0 + a1) + (a2 + a3) + ba1[j];
  sH[half * 128 + j] = h > 0.f ? h : 0.f;
  __syncthreads();
  if (tid < 6) {
    int hh = tid / 3, l = tid % 3;
    const float* w2 = Wa2 + l * 128;
    const float* hv = sH + hh * 128;
    float s = 0.f;
    for (int k = 0; k < 128; ++k) s = fmaf(w2[k], hv[k], s);
    aw[(size_t)(rs0 + hh) * 3 + l] = s + ba2[l];
  }
}

// ---------------- K2b: softmax over time (axis s) per (b, l), in-place ----------------
__global__ __launch_bounds__(256) void k_softmax(float* __restrict__ aw)
{
  __shared__ float red[256];
  const int b = blockIdx.x / 3, l = blockIdx.x % 3;
  const int tid = threadIdx.x;
  float v[4];
#pragma unroll
  for (int i = 0; i < 4; ++i) {
    int s = tid + i * 256;
    v[i] = aw[(size_t)(s * 32 + b) * 3 + l];
  }
  float mx = fmaxf(fmaxf(v[0], v[1]), fmaxf(v[2], v[3]));
  red[tid] = mx;
  __syncthreads();
  for (int off = 128; off > 0; off >>= 1) {
    if (tid < off) red[tid] = fmaxf(red[tid], red[tid + off]);
    __syncthreads();
  }
  mx = red[0];
  __syncthreads();
  float sm = 0.f;
#pragma unroll
  for (int i = 0; i < 4; ++i) sm += __expf(v[i] - mx);
  red[tid] = sm;
  __syncthreads();
  for (int off = 128; off > 0; off >>= 1) {
    if (tid < off) red[tid] += red[tid + off];
    __syncthreads();
  }
  float inv = 1.f / red[0];
#pragma unroll
  for (int i = 0; i < 4; ++i) {
    int s = tid + i * 256;
    aw[(size_t)(s * 32 + b) * 3 + l] = __expf(v[i] - mx) * inv;
  }
}

// ---------------- K_prep: repack Wih_d (516-stride, aligned) + pre-summed biases ----------------
__global__ __launch_bounds__(256) void k_prep(
    const float* __restrict__ Wih_d,
    const float* __restrict__ bih_e, const float* __restrict__ bhh_e,
    const float* __restrict__ bih_d, const float* __restrict__ bhh_d,
    float* __restrict__ wdpack, float* __restrict__ bsum_e, float* __restrict__ bsum_d)
{
  const int row = blockIdx.x;           // 2048 rows
  const int tid = threadIdx.x;
  for (int q = tid; q < 516; q += 256) {
    float v = 0.f;
    if (q < 512)      v = Wih_d[(size_t)row * 513 + 1 + q];   // ctx part
    else if (q == 512) v = Wih_d[(size_t)row * 513];          // p coefficient
    wdpack[(size_t)row * 516 + q] = v;
  }
  if (tid == 0) {
    bsum_e[row] = bih_e[row] + bhh_e[row];
    bsum_d[row] = bih_d[row] + bhh_d[row];
  }
}

// ---------------- K_init: initial states + d_out = b_o2 + barrier zero ----------------
__global__ __launch_bounds__(256) void k_init(
    const float* __restrict__ eh0, const float* __restrict__ dh0,
    const float* __restrict__ bo2,
    float* __restrict__ heb, float* __restrict__ hdb,
    float* __restrict__ out, unsigned* __restrict__ bar)
{
  const int i = blockIdx.x * 256 + threadIdx.x;   // 32768 threads
  if (i < 16384) {
    int k = i & 511;
    heb[16384 + i] = eh0[k];   // slot 1 == slot for t=-1
    hdb[i] = dh0[k];           // single buffer, holds h_d(t-1)
  }
  out[i] = bo2[0];
  if (i < 1024) bar[i] = 0u;
}

// ---------------- group barrier: 64 wgs, two-level counter, UC atomics, NO cache fences ----
// All cross-wg data moves via relaxed agent-scope atomics (live at the coherence point),
// so no wbl2/inv is ever needed -> weights stay hot in L2. __syncthreads() + s_waitcnt(0)
// drain each wave's outstanding stores before the arrival RMW.
// Layout per group (dword offsets from gbar): sub-counters at s*16 (s=0..7, 64B apart),
// top counter at 128. Spin on top == gen*8 (8 sub-finishers per generation).
__device__ __forceinline__ void groupbar(unsigned* gbar, int r, unsigned gen)
{
  __builtin_amdgcn_s_waitcnt(0);
  __syncthreads();
  if (threadIdx.x == 0) {
    asm volatile("" ::: "memory");
    unsigned old = AGADD(gbar + ((r >> 3) << 4), 1u);
    if (old == (gen << 3) - 1u)          // last of this sub-group of 8 wgs
      (void)AGADD(gbar + 128, 1u);
    while (AGLD(gbar + 128) < (gen << 3))
      __builtin_amdgcn_s_sleep(1);
    asm volatile("" ::: "memory");
  }
  __syncthreads();
}

// out-MLP duty for time index TI (only wgs with r < 16; 8 e-dims x 8 batches per wg).
// thread = (e = tid>>5, ob = (tid>>2)&7, kq = tid&3); partial 128-dot, 4-lane shuffle
// reduce, relu*Wo2 at kq==0, pair-sum across e-halves, per-wave LDS partials, one
// atomicAdd per (wg, batch)  -> only 16 contending adds per output scalar.
#define OUT_DUTY(TI) do { \
    const int e_ = (r << 3) + (tid >> 5); \
    const int ob_ = (tid >> 2) & 7; \
    const int kq_ = tid & 3; \
    const float* wo_ = Wo1 + (size_t)e_ * 512 + (kq_ << 7); \
    const float* hd_ = sHd + ob_ * 516 + (kq_ << 7); \
    float a0 = 0.f, a1 = 0.f, a2 = 0.f, a3 = 0.f; \
    _Pragma("unroll") \
    for (int k = 0; k < 128; k += 16) DOT16(wo_, hd_, k); \
    float p_ = (a0 + a1) + (a2 + a3); \
    p_ += __shfl_down(p_, 1); \
    p_ += __shfl_down(p_, 2); \
    float contrib_ = 0.f; \
    if (kq_ == 0) { \
      float q_ = p_ + bo1[e_]; \
      contrib_ = (q_ > 0.f ? q_ : 0.f) * Wo2[e_]; \
    } \
    contrib_ += __shfl_down(contrib_, 32); \
    { \
      const int lane_ = tid & 63, wv_ = tid >> 6; \
      if (lane_ < 32 && (lane_ & 3) == 0) sRed[(wv_ << 3) + (lane_ >> 2)] = contrib_; \
    } \
    __syncthreads(); \
    if (tid < 8) \
      atomicAdd(&out[(size_t)(gb8 + tid) * 1024 + (TI)], \
                sRed[tid] + sRed[8 + tid] + sRed[16 + tid] + sRed[24 + tid]); \
  } while (0)

// ---------------- K_persist: 4 batch-groups x 64 row-slices, batched matvecs ----------------
// wg = (g = blockIdx>>6, r = blockIdx&63). Group g owns batches [g*8, g*8+8); slice r owns
// h-dims [r*8, r*8+8) of BOTH LSTMs (gate rows gamma*512 + r*8 + d). Each wg computes its
// 32 gate rows for ALL 8 batches of its group (thread = row*8 + batch), so each weight
// float4 is loaded once per wave and broadcast to 8 same-row lanes: 8x less L2 weight
// traffic than batch-per-wg. r%8 == blockIdx%8 pins each slice to one XCD (both groups of
// a slice on the same XCD) -> ~1.7 MB of weight rows stay L2-resident per XCD.
__global__ __launch_bounds__(256) void k_persist(
    const float* __restrict__ emb, const float* __restrict__ aw,
    const int* __restrict__ lens,
    const float* __restrict__ Wih_e, const float* __restrict__ Whh_e,
    const float* __restrict__ Whh_d, const float* __restrict__ wdpack,
    const float* __restrict__ bsum_e, const float* __restrict__ bsum_d,
    const float* __restrict__ ec0, const float* __restrict__ dc0,
    const float* __restrict__ Wo1, const float* __restrict__ bo1,
    const float* __restrict__ Wo2, const float* __restrict__ maskp,
    float* __restrict__ heb, float* __restrict__ hdb,
    float* __restrict__ ctxb, float* __restrict__ out,
    unsigned* __restrict__ bar)
{
  __shared__ float sX[8 * 516];    // phase A: h_e(t-1); phase B: ctx(t). 516-stride: pad
  __shared__ float sHd[8 * 516];   //   -> float4 reads hit distinct banks per batch lane.
  __shared__ float sEmb[8 * 132];
  __shared__ float sG[256];
  __shared__ float sP[8];
  __shared__ float sRed[32];

  const int tid = threadIdx.x;
  const int g = blockIdx.x >> 6;        // batch group 0..3
  const int r = blockIdx.x & 63;        // row slice 0..63
  const int rr = tid >> 3;              // gate-row within slice 0..31 (gamma*8 + d)
  const int bb = tid & 7;               // batch within group 0..7
  const int grow = ((rr >> 3) << 9) + (r << 3) + (rr & 7);
  const int gb8 = g << 3;

  unsigned* gbar = bar + g * 160;

  // per-thread persistent row constants
  const float be_row = bsum_e[grow];
  const float bd_row = bsum_d[grow];
  const float pcoef  = wdpack[(size_t)grow * 516 + 512];

  // cell-state registers: tid < 64 owns (dim = r*8 + tid>>3, batch = gb8 + (tid&7))
  float c_e = 0.f, c_d = 0.f, hm1 = 0.f, hm2 = 0.f;
  int len_b = 0;
  if (tid < 64) {
    int dim = (r << 3) + (tid >> 3);
    c_e = ec0[dim];
    c_d = dc0[dim];
    len_b = lens[gb8 + (tid & 7)];
  }

  const float* whe = Whh_e + (size_t)grow * 512;
  const float* wie = Wih_e + (size_t)grow * 128;
  const float* whd = Whh_d + (size_t)grow * 512;
  const float* wdc = wdpack + (size_t)grow * 516;
  const float* hX  = sX   + bb * 516;
  const float* hD  = sHd  + bb * 516;
  const float* hE  = sEmb + bb * 132;

  unsigned gen = 0;

  for (int t = 0; t < 1024; ++t) {
    // ================= phase A =================
    {  // stage h_e(t-1), h_d(t-1) for the group's 8 batches (UC) + emb[t] (cached)
      const float* hep = heb + (size_t)((t + 1) & 1) * 16384 + (size_t)gb8 * 512;
      const float* hdp = hdb + (size_t)gb8 * 512;
      float vHe[16], vHd[16];
#pragma unroll
      for (int j = 0; j < 16; ++j) {
        vHe[j] = AGLD(hep + tid + j * 256);
        vHd[j] = AGLD(hdp + tid + j * 256);
      }
      float4 ev = *(const float4*)(emb + (size_t)(t * 32 + gb8 + (tid >> 5)) * 128 + ((tid & 31) << 2));
#pragma unroll
      for (int j = 0; j < 16; ++j) {
        int i = tid + j * 256, bi = i >> 9, kk = i & 511;
        sX [bi * 516 + kk] = vHe[j];
        sHd[bi * 516 + kk] = vHd[j];
      }
      *(float4*)(sEmb + (tid >> 5) * 132 + ((tid & 31) << 2)) = ev;
    }
    __syncthreads();

    // encoder gates: each thread = one (row, batch) full 640-dot
    {
      float a0 = 0.f, a1 = 0.f, a2 = 0.f, a3 = 0.f;
#pragma unroll 4
      for (int k = 0; k < 512; k += 16) DOT16(whe, hX, k);
#pragma unroll
      for (int k = 0; k < 128; k += 16) DOT16(wie, hE, k);
      sG[(rr << 3) + bb] = (a0 + a1) + (a2 + a3) + be_row;
    }

    // out-MLP duty for step t-1 (from staged sHd = h_d(t-1))
    if (r < 16 && t > 0) { OUT_DUTY(t - 1); }

    __syncthreads();

    // enc cell + publish h_e slice and ctx slice (UC)
    if (tid < 64) {
      float gi = sG[tid], gf = sG[64 + tid], gg = sG[128 + tid], go = sG[192 + tid];
      c_e = sigm(gf) * c_e + sigm(gi) * tanh_(gg);
      float h = sigm(go) * tanh_(c_e);
      int dim = (r << 3) + (tid >> 3);
      int gb = gb8 + (tid & 7);
      AGST(&heb[(size_t)(t & 1) * 16384 + (size_t)gb * 512 + dim], h);
      float hmv = (t < len_b) ? h : 0.f;
      const float* at = aw + (size_t)(t * 32 + gb) * 3;
      float ctx = at[0] * hmv + at[1] * hm1 + at[2] * hm2;
      hm2 = hm1; hm1 = hmv;
      AGST(&ctxb[(size_t)gb * 512 + dim], ctx);
    }
    groupbar(gbar, r, ++gen);

    // ================= phase B =================
    {  // stage ctx(t) (UC, overwrites sX) + p(t-1)
      const float* cp = ctxb + (size_t)gb8 * 512;
      float vC[16];
#pragma unroll
      for (int j = 0; j < 16; ++j) vC[j] = AGLD(cp + tid + j * 256);
#pragma unroll
      for (int j = 0; j < 16; ++j) {
        int i = tid + j * 256, bi = i >> 9, kk = i & 511;
        sX[bi * 516 + kk] = vC[j];
      }
      if (tid < 8) sP[tid] = (t == 0) ? 0.f : AGLD(&out[(size_t)(gb8 + tid) * 1024 + (t - 1)]);
    }
    __syncthreads();

    // decoder gates (sHd still holds h_d(t-1))
    {
      float a0 = 0.f, a1 = 0.f, a2 = 0.f, a3 = 0.f;
#pragma unroll 2
      for (int k = 0; k < 512; k += 16) { DOT16(whd, hD, k); DOT16(wdc, hX, k); }
      sG[(rr << 3) + bb] = (a0 + a1) + (a2 + a3) + pcoef * sP[bb] + bd_row;
    }
    __syncthreads();

    // dec cell + publish h_d slice (UC)
    if (tid < 64) {
      float gi = sG[tid], gf = sG[64 + tid], gg = sG[128 + tid], go = sG[192 + tid];
      c_d = sigm(gf) * c_d + sigm(gi) * tanh_(gg);
      float h = sigm(go) * tanh_(c_d);
      int dim = (r << 3) + (tid >> 3);
      AGST(&hdb[(size_t)(gb8 + (tid & 7)) * 512 + dim], h);
    }
    groupbar(gbar, r, ++gen);
  }

  // ---- final out-MLP duty for t = 1023 ----
  if (r < 16) {
    const float* hdp = hdb + (size_t)gb8 * 512;
    float vHd[16];
#pragma unroll
    for (int j = 0; j < 16; ++j) vHd[j] = AGLD(hdp + tid + j * 256);
#pragma unroll
    for (int j = 0; j < 16; ++j) {
      int i = tid + j * 256, bi = i >> 9, kk = i & 511;
      sHd[bi * 516 + kk] = vHd[j];
    }
    __syncthreads();
    OUT_DUTY(1023);
  }
  groupbar(gbar, r, ++gen);

  // ---- mask own chunk: 128 outputs per wg, within this group's batches ----
  if (tid < 128) {
    int idx = blockIdx.x * 128 + tid;
    float v = AGLD(&out[idx]);
    out[idx] = v * maskp[idx];
  }
}

extern "C" void kernel_launch(void* const* d_in, const int* in_sizes, int n_in,
                              void* d_out, int out_size, void* d_ws, size_t ws_size,
                              hipStream_t stream)
{
  const float* inp   = (const float*)d_in[0];
  const float* maskp = (const float*)d_in[1];
  const int*   lens  = (const int*)d_in[2];
  const float* We    = (const float*)d_in[3];
  const float* be    = (const float*)d_in[4];
  const float* Wa1   = (const float*)d_in[5];
  const float* ba1   = (const float*)d_in[6];
  const float* Wa2   = (const float*)d_in[7];
  const float* ba2   = (const float*)d_in[8];
  const float* Wih_e = (const float*)d_in[9];
  const float* Whh_e = (const float*)d_in[10];
  const float* bih_e = (const float*)d_in[11];
  const float* bhh_e = (const float*)d_in[12];
  const float* eh0   = (const float*)d_in[13];
  const float* ec0   = (const float*)d_in[14];
  const float* Wih_d = (const float*)d_in[15];
  const float* Whh_d = (const float*)d_in[16];
  const float* bih_d = (const float*)d_in[17];
  const float* bhh_d = (const float*)d_in[18];
  const float* dh0   = (const float*)d_in[19];
  const float* dc0   = (const float*)d_in[20];
  const float* Wo1   = (const float*)d_in[21];
  const float* bo1   = (const float*)d_in[22];
  const float* Wo2   = (const float*)d_in[23];
  const float* bo2   = (const float*)d_in[24];

  float* ws     = (float*)d_ws;
  float* emb    = ws;                     // 4,194,304
  float* aw     = emb + 4194304;          //    98,304
  float* heb    = aw + 98304;             //    32,768 (2 slots)
  float* hdb    = heb + 32768;            //    16,384
  float* ctxb   = hdb + 16384;            //    16,384
  float* wdpack = ctxb + 16384;           // 1,056,768 (2048 x 516)
  float* bsum_e = wdpack + 1056768;       //     2,048
  float* bsum_d = bsum_e + 2048;          //     2,048
  unsigned* bar = (unsigned*)(bsum_d + 2048);  // 1,024 (4 groups x 160 used)
  float* outf = (float*)d_out;

  k_embed<<<512, 256, 0, stream>>>(inp, We, be, emb);
  k_attn<<<16384, 256, 0, stream>>>(emb, Wa1, ba1, Wa2, ba2, aw);
  k_softmax<<<96, 256, 0, stream>>>(aw);
  k_prep<<<2048, 256, 0, stream>>>(Wih_d, bih_e, bhh_e, bih_d, bhh_d,
                                   wdpack, bsum_e, bsum_d);
  k_init<<<128, 256, 0, stream>>>(eh0, dh0, bo2, heb, hdb, outf, bar);

  k_persist<<<256, 256, 0, stream>>>(
      emb, aw, lens,
      Wih_e, Whh_e, Whh_d, wdpack, bsum_e, bsum_d,
      ec0, dc0, Wo1, bo1, Wo2, maskp,
      heb, hdb, ctxb, outf, bar);
}